// Round 15
// baseline (36.167 us; speedup 1.0000x reference)
//
#include <hip/hip_runtime.h>
#include <hip/hip_bf16.h>

#define DD 512   // feature dim
#define H1 256   // hidden 1
#define H2 128   // hidden 2
#define CC 20    // real classes
#define CP 24    // padded classes
#define QPB 8    // queries per block (512 threads)
#define HROWS (QPB*CP)   // 192 h1 rows per block
#define PSTR 132         // Pmat row stride (floats)
#define NDC 4            // fallback split-K
#define DCH (DD/NDC)
#define CSB 40           // class-sum blocks (2/class) in 2-kernel path
#define NPROD 61         // fused-path producer blocks: 20 qbc + 1 stats + 32 w1f + 8 w2f
#define MAGIC 0x5A5A5A5Au

typedef short v8s __attribute__((ext_vector_type(8)));
typedef float v4f __attribute__((ext_vector_type(4)));

// ---- fast-path ws float offsets ----
#define NSTAT    97
#define OFF_ST2  0
#define OFF_QBC  128                   // 20x512 bf16 = 5120 float slots
#define OFF_W1F  5248                  // 131072 bf16 = 65536 float slots
#define OFF_W2F  70784                 // 32768 bf16 = 16384 float slots
#define OFF_MRK  87168                 // 61 marker words
#define REQ_FAST (87168 + 64)
// ---- legacy fallback ws float offsets ----
#define OFF_SUMF 0
#define OFF_B1C  10240
#define OFF_H10  16384
#define OFF_PRE  16640
#define OFF_ST   19200
#define OFF_U    19328

static __device__ __forceinline__ unsigned short f2b(float f) {
  return __bfloat16_as_ushort(__float2bfloat16(f));
}
static __device__ __forceinline__ float b2f(unsigned short s) {
  return __bfloat162float(__ushort_as_bfloat16(s));
}

static __device__ __forceinline__ void stats_store(
    const int* __restrict__ labels, int S, float* __restrict__ stats, int t) {
  if (t < CP) {
    int cnt = 0;
    for (int j = 0; j < S; ++j) if (labels[j] == t) cnt++;
    float deg  = 1.f + (float)cnt;
    float dis  = rsqrtf(deg + 1e-6f);
    float dis0 = rsqrtf((float)S + 1e-6f);
    stats[1 + t]          = dis;
    stats[1 + CP + t]     = dis0 * dis;               // alpha
    stats[1 + 2*CP + t]   = dis * dis * (float)cnt;   // beta (0 pad)
    stats[1 + 3*CP + t]   = dis * (float)cnt;         // gamma (0 pad)
    if (t == 0) stats[0] = dis0;
  }
}

static __device__ __forceinline__ void w1frag_store(
    const float* __restrict__ W1, unsigned short* __restrict__ w1f, int frag, int l) {
  int lr = l & 15, lg = l >> 4;
  int nt = frag >> 4, ks = frag & 15;
  __align__(16) unsigned short o[8];
#pragma unroll
  for (int e = 0; e < 8; ++e)
    o[e] = f2b(W1[(ks * 32 + lg * 8 + e) * H1 + nt * 16 + lr]);
  *(v8s*)&w1f[frag * 512 + l * 8] = *(const v8s*)o;
}

static __device__ __forceinline__ void w2frag_store(
    const float* __restrict__ W2, unsigned short* __restrict__ w2f, int frag, int l) {
  int lr = l & 15, lg = l >> 4;
  int nt = frag >> 3, ks = frag & 7;
  __align__(16) unsigned short o[8];
#pragma unroll
  for (int e = 0; e < 8; ++e)
    o[e] = f2b(W2[(ks * 32 + lg * 8 + e) * H2 + nt * 16 + lr]);
  *(v8s*)&w2f[frag * 512 + l * 8] = *(const v8s*)o;
}

// ===================== k_fused: single launch, producer/consumer via markers =============
// grid == nb blocks (61 <= nb <= 256), 512 thr, ~101KB LDS -> 1 block/CU, all co-resident.
__global__ __launch_bounds__(512, 1) void k_fused(
    const float* __restrict__ Sf, const int* __restrict__ labels, int S,
    const float* __restrict__ qf, const float* __restrict__ W1,
    const float* __restrict__ W2, const float* __restrict__ b1,
    const float* __restrict__ b2,
    unsigned short* __restrict__ qbc, unsigned short* __restrict__ w1f,
    unsigned short* __restrict__ w2f, float* __restrict__ stats,
    unsigned int* __restrict__ mrk, float* __restrict__ out, int Q) {
  __shared__ float smem[HROWS * PSTR];           // A-tile, then hb/Pm (aliased)
  __shared__ unsigned short u_all[28 * H1];      // bf16 U rows (8q + 20c)
  __shared__ float stc[NSTAT];
  __shared__ __align__(16) float b1l[H1];
  __shared__ float b2l[H2];
  __shared__ float qe[QPB * H2];
  __shared__ float qn[QPB];
  __shared__ int lab[128];
  unsigned short* ab = (unsigned short*)smem;    // A-tile bf16 [32][512], XOR-swizzled
  unsigned short* hb = (unsigned short*)smem;    // h1 bf16 [192][256], XOR-swizzled
  float* Pm = smem;

  int b = blockIdx.x, t = threadIdx.x, q0 = b * QPB;

  // ---------- producer slice (blocks 0..NPROD-1) ----------
  if (b < 20) {
    if (t < S && t < 128) lab[t] = labels[t];
    __syncthreads();
    float acc = 0.f;
    for (int j = 0; j < S; ++j)
      if (lab[j] == b) acc += Sf[(size_t)j * DD + t];   // wave-uniform branch
    qbc[b * DD + t] = f2b(acc);
    __syncthreads();
    __threadfence();
    if (t == 0) atomicExch(&mrk[b], MAGIC);
  } else if (b == 20) {
    stats_store(labels, S, stats, t);
    __syncthreads();
    __threadfence();
    if (t == 0) atomicExch(&mrk[20], MAGIC);
  } else if (b < 53) {
    w1frag_store(W1, w1f, (b - 21) * 8 + (t >> 6), t & 63);
    __syncthreads();
    __threadfence();
    if (t == 0) atomicExch(&mrk[b], MAGIC);
  } else if (b < NPROD) {
    w2frag_store(W2, w2f, (b - 53) * 8 + (t >> 6), t & 63);
    __syncthreads();
    __threadfence();
    if (t == 0) atomicExch(&mrk[b], MAGIC);
  }

  // ---------- stage query rows (conv-independent) + biases ----------
  if (t < H1) b1l[t] = b1[t];
  if (t >= 128 && t < 256) b2l[t - 128] = b2[t - 128];
  {
    int row = t >> 6, jc = t & 63;               // rows 0..7
    __align__(16) unsigned short o[8];
    if (q0 + row < Q) {
      const float4 a = *(const float4*)&qf[(size_t)(q0 + row) * DD + jc * 8];
      const float4 c = *(const float4*)&qf[(size_t)(q0 + row) * DD + jc * 8 + 4];
      o[0]=f2b(a.x); o[1]=f2b(a.y); o[2]=f2b(a.z); o[3]=f2b(a.w);
      o[4]=f2b(c.x); o[5]=f2b(c.y); o[6]=f2b(c.z); o[7]=f2b(c.w);
    } else {
#pragma unroll
      for (int e = 0; e < 8; ++e) o[e] = 0;
    }
    // NOTE: producers used smem for lab (bytes 0..511); query rows start at ab[0] too,
    // but lab use is fully fenced by the __syncthreads above before this store.
    *(v8s*)&ab[(row * DD + jc * 8) ^ ((row & 7) << 3)] = *(const v8s*)o;
  }

  // ---------- acquire: wait for all producers (instant on replays) ----------
  if (t < NPROD) {
    while (atomicAdd(&mrk[t], 0u) != MAGIC) __builtin_amdgcn_s_sleep(8);
    __threadfence();
  }
  __syncthreads();

  // ---------- stage class rows + pad, load stats ----------
  if (t < NSTAT) stc[t] = stats[t];
#pragma unroll
  for (int i = 1; i < 4; ++i) {
    int ch = t + 512 * i;
    int row = ch >> 6, jc = ch & 63;
    if (row < QPB + CC) {
      v8s v = *(const v8s*)&qbc[(row - QPB) * DD + jc * 8];
      *(v8s*)&ab[(row * DD + jc * 8) ^ ((row & 7) << 3)] = v;
    } else {
      v8s z = (v8s){0,0,0,0,0,0,0,0};
      *(v8s*)&ab[(row * DD + jc * 8) ^ ((row & 7) << 3)] = z;
    }
  }
  __syncthreads();

  // ---- U-GEMM: [32 x 512] @ W1 -> u_all[28][256]; wave w owns N-tiles {2w, 2w+1} ----
  int w = t >> 6, l = t & 63, lr = l & 15, lg = l >> 4;
  {
    v4f ua[2][2];
#pragma unroll
    for (int mt = 0; mt < 2; ++mt)
#pragma unroll
      for (int nt = 0; nt < 2; ++nt) ua[mt][nt] = (v4f){0.f, 0.f, 0.f, 0.f};
#pragma unroll 2
    for (int ks = 0; ks < 16; ++ks) {
      const v8s a0 = *(const v8s*)&ab[((0  + lr) * DD + ks * 32 + lg * 8) ^ ((lr & 7) << 3)];
      const v8s a1 = *(const v8s*)&ab[((16 + lr) * DD + ks * 32 + lg * 8) ^ ((lr & 7) << 3)];
#pragma unroll
      for (int nt = 0; nt < 2; ++nt) {
        const v8s bb = *(const v8s*)&w1f[((w * 2 + nt) * 16 + ks) * 512 + l * 8];
        ua[0][nt] = __builtin_amdgcn_mfma_f32_16x16x32_bf16(a0, bb, ua[0][nt], 0, 0, 0);
        ua[1][nt] = __builtin_amdgcn_mfma_f32_16x16x32_bf16(a1, bb, ua[1][nt], 0, 0, 0);
      }
    }
#pragma unroll
    for (int mt = 0; mt < 2; ++mt)
#pragma unroll
      for (int nt = 0; nt < 2; ++nt)
#pragma unroll
        for (int r = 0; r < 4; ++r) {
          int row = mt * 16 + lg * 4 + r;
          if (row < QPB + CC)
            u_all[row * H1 + (w * 2 + nt) * 16 + lr] = f2b(ua[mt][nt][r]);
        }
  }
  __syncthreads();   // A-tile dead; u_all ready; smem free for hb

  // ---- h10 row (hb row 20, q=0 pad slot, gamma=0): 256 threads in parallel ----
  if (t < 256) {
    float s = 0.f;
#pragma unroll
    for (int c2 = 0; c2 < CC; ++c2)
      s = fmaf(stc[1 + c2], b2f(u_all[(QPB + c2) * H1 + t]), s);
    float h = fmaxf(fmaf(stc[0], s, b1l[t]), 0.f);
    hb[(((20 * 256) + (t & ~7)) ^ 32) + (t & 7)] = f2b(h);
  }

  // ---- h1 build (bf16, XOR-swizzled); r==20 handled above ----
#pragma unroll 4
  for (int i = 0; i < 12; ++i) {
    int ch = t + 512 * i;
    int r = ch >> 5, jc = ch & 31;
    int q = r / 24, c = r - q * 24;
    int j0 = jc * 8;
    int cs = (c < CC) ? c : 0;                   // clamp pad rows (finite, unused)
    float al = stc[1 + CP + c];
    float dc = stc[1 + cs], sc = dc * dc;
    const v8s uv = *(const v8s*)&u_all[q * H1 + j0];
    const v8s ev = *(const v8s*)&u_all[(QPB + cs) * H1 + j0];
    __align__(16) unsigned short o[8];
#pragma unroll
    for (int e = 0; e < 8; ++e) {
      float u = b2f((unsigned short)uv[e]);
      float x = b2f((unsigned short)ev[e]);
      o[e] = f2b(fmaxf(fmaf(al, u, fmaf(sc, x, b1l[j0 + e])), 0.f));
    }
    if (r != 20)
      *(v8s*)&hb[(r * 256 + j0) ^ ((r & 7) << 3)] = *(const v8s*)o;
  }
  __syncthreads();

  // ---- P-GEMM: 2D wave split (wm,wn) = (w>>2, w&3); 6 M-tiles x 2 N-tiles x 8 ks ----
  int wm = w >> 2, wn = w & 3;
  v4f acc[6][2];
#pragma unroll
  for (int mt = 0; mt < 6; ++mt) {
    acc[mt][0] = (v4f){0.f, 0.f, 0.f, 0.f};
    acc[mt][1] = (v4f){0.f, 0.f, 0.f, 0.f};
  }
#pragma unroll
  for (int ks = 0; ks < 8; ++ks) {
    const v8s bb0 = *(const v8s*)&w2f[(((wn * 2 + 0) * 8) + ks) * 512 + l * 8];
    const v8s bb1 = *(const v8s*)&w2f[(((wn * 2 + 1) * 8) + ks) * 512 + l * 8];
#pragma unroll
    for (int mt = 0; mt < 6; ++mt) {
      int row = wm * 96 + mt * 16 + lr;
      const v8s a = *(const v8s*)&hb[(row * 256 + ks * 32 + lg * 8) ^ ((row & 7) << 3)];
      acc[mt][0] = __builtin_amdgcn_mfma_f32_16x16x32_bf16(a, bb0, acc[mt][0], 0, 0, 0);
      acc[mt][1] = __builtin_amdgcn_mfma_f32_16x16x32_bf16(a, bb1, acc[mt][1], 0, 0, 0);
    }
  }
  __syncthreads();   // hb reads done -> alias as Pmat

#pragma unroll
  for (int mt = 0; mt < 6; ++mt)
#pragma unroll
    for (int nt = 0; nt < 2; ++nt)
#pragma unroll
      for (int r = 0; r < 4; ++r)
        Pm[(wm * 96 + mt * 16 + lg * 4 + r) * PSTR + (wn * 2 + nt) * 16 + lr]
            = acc[mt][nt][r];
  __syncthreads();
  // Pm[20][k] == g2[k] = h10 @ W2[:,k]

#pragma unroll
  for (int rep = 0; rep < 2; ++rep) {
    int idx = t + 512 * rep;
    int q = idx >> 7, k = idx & 127;
    float s = 0.f;
#pragma unroll
    for (int c = 0; c < CC; ++c) s = fmaf(stc[1 + 3 * CP + c], Pm[(q * 24 + c) * PSTR + k], s);
    qe[q * H2 + k] = fmaxf(fmaf(stc[0], s, b2l[k]), 0.f);
  }
  __syncthreads();

  if (t < 256) {
    int q = t >> 5, ln = t & 31;
    float s = 0.f;
#pragma unroll
    for (int i = 0; i < 4; ++i) { float e = qe[q * H2 + ln + 32 * i]; s = fmaf(e, e, s); }
    s += __shfl_xor(s, 1); s += __shfl_xor(s, 2); s += __shfl_xor(s, 4);
    s += __shfl_xor(s, 8); s += __shfl_xor(s, 16);
    if (ln == 0) qn[q] = s;
  }
  __syncthreads();

#pragma unroll
  for (int rep = 0; rep < 2; ++rep) {
    int idx = t + 512 * rep;
    int q = idx >> 7;
    int sub = idx & 127, c = sub >> 2, lcl = sub & 3;
    if (c < CC && q0 + q < Q) {
      float num = 0.f, pn = 0.f;
      int rowb = (q * 24 + c) * PSTR;
      float bet = stc[1 + 2 * CP + c];
      float d0dc = stc[0] * stc[1 + c];
#pragma unroll
      for (int i = 0; i < 32; ++i) {
        int k = lcl + 4 * i;
        float P = Pm[rowb + k];
        float pr = fmaxf(fmaf(bet, P, fmaf(d0dc, Pm[20 * PSTR + k], b2l[k])), 0.f);
        float e = qe[q * H2 + k];
        num = fmaf(e, pr, num); pn = fmaf(pr, pr, pn);
      }
      num += __shfl_xor(num, 1); pn += __shfl_xor(pn, 1);
      num += __shfl_xor(num, 2); pn += __shfl_xor(pn, 2);
      if (lcl == 0)
        out[(size_t)(q0 + q) * CC + c] = num / fmaxf(sqrtf(qn[q]) * sqrtf(pn), 1e-8f);
    }
  }
}

// ===================== 2-kernel path (r14-proven) for non-matching shapes ================
__global__ __launch_bounds__(256) void k_conv2(
    const float* __restrict__ Sf, const int* __restrict__ labels, int S,
    const float* __restrict__ W1, const float* __restrict__ W2,
    unsigned short* __restrict__ qbc, unsigned short* __restrict__ w1f,
    unsigned short* __restrict__ w2f, float* __restrict__ stats) {
  int b = blockIdx.x, t = threadIdx.x;
  if (b < CSB) {
    __shared__ int lab[128];
    if (t < S && t < 128) lab[t] = labels[t];
    __syncthreads();
    int c = b >> 1;
    int d = (b & 1) * 256 + t;
    float acc = 0.f;
    for (int j = 0; j < S; ++j)
      if (lab[j] == c) acc += Sf[(size_t)j * DD + d];
    qbc[c * DD + d] = f2b(acc);
  } else if (b == CSB) {
    stats_store(labels, S, stats, t);
  } else if (b < CSB + 1 + 64) {
    w1frag_store(W1, w1f, (b - CSB - 1) * 4 + (t >> 6), t & 63);
  } else {
    w2frag_store(W2, w2f, (b - CSB - 1 - 64) * 4 + (t >> 6), t & 63);
  }
}

__global__ __launch_bounds__(512, 1) void k_main(
    const float* __restrict__ qf,
    const float* __restrict__ b1, const float* __restrict__ b2,
    const unsigned short* __restrict__ qbc, const unsigned short* __restrict__ w1f,
    const unsigned short* __restrict__ w2f, const float* __restrict__ stats,
    float* __restrict__ out, int Q) {
  __shared__ float smem[HROWS * PSTR];
  __shared__ unsigned short u_all[28 * H1];
  __shared__ float stc[NSTAT];
  __shared__ __align__(16) float b1l[H1];
  __shared__ float b2l[H2];
  __shared__ float qe[QPB * H2];
  __shared__ float qn[QPB];
  unsigned short* ab = (unsigned short*)smem;
  unsigned short* hb = (unsigned short*)smem;
  float* Pm = smem;

  int t = threadIdx.x, q0 = blockIdx.x * QPB;
  if (t < NSTAT) stc[t] = stats[t];
  if (t < H1) b1l[t] = b1[t];
  if (t >= 128 && t < 256) b2l[t - 128] = b2[t - 128];

#pragma unroll
  for (int i = 0; i < 4; ++i) {
    int ch = t + 512 * i;
    int row = ch >> 6, jc = ch & 63;
    __align__(16) unsigned short o[8];
    if (row < QPB) {
      if (q0 + row < Q) {
        const float4 a = *(const float4*)&qf[(size_t)(q0 + row) * DD + jc * 8];
        const float4 c = *(const float4*)&qf[(size_t)(q0 + row) * DD + jc * 8 + 4];
        o[0]=f2b(a.x); o[1]=f2b(a.y); o[2]=f2b(a.z); o[3]=f2b(a.w);
        o[4]=f2b(c.x); o[5]=f2b(c.y); o[6]=f2b(c.z); o[7]=f2b(c.w);
      } else {
#pragma unroll
        for (int e = 0; e < 8; ++e) o[e] = 0;
      }
      *(v8s*)&ab[(row * DD + jc * 8) ^ ((row & 7) << 3)] = *(const v8s*)o;
    } else if (row < QPB + CC) {
      v8s v = *(const v8s*)&qbc[(row - QPB) * DD + jc * 8];
      *(v8s*)&ab[(row * DD + jc * 8) ^ ((row & 7) << 3)] = v;
    } else {
      v8s z = (v8s){0,0,0,0,0,0,0,0};
      *(v8s*)&ab[(row * DD + jc * 8) ^ ((row & 7) << 3)] = z;
    }
  }
  __syncthreads();

  int w = t >> 6, l = t & 63, lr = l & 15, lg = l >> 4;
  {
    v4f ua[2][2];
#pragma unroll
    for (int mt = 0; mt < 2; ++mt)
#pragma unroll
      for (int nt = 0; nt < 2; ++nt) ua[mt][nt] = (v4f){0.f, 0.f, 0.f, 0.f};
#pragma unroll 2
    for (int ks = 0; ks < 16; ++ks) {
      const v8s a0 = *(const v8s*)&ab[((0  + lr) * DD + ks * 32 + lg * 8) ^ ((lr & 7) << 3)];
      const v8s a1 = *(const v8s*)&ab[((16 + lr) * DD + ks * 32 + lg * 8) ^ ((lr & 7) << 3)];
#pragma unroll
      for (int nt = 0; nt < 2; ++nt) {
        const v8s bb = *(const v8s*)&w1f[((w * 2 + nt) * 16 + ks) * 512 + l * 8];
        ua[0][nt] = __builtin_amdgcn_mfma_f32_16x16x32_bf16(a0, bb, ua[0][nt], 0, 0, 0);
        ua[1][nt] = __builtin_amdgcn_mfma_f32_16x16x32_bf16(a1, bb, ua[1][nt], 0, 0, 0);
      }
    }
#pragma unroll
    for (int mt = 0; mt < 2; ++mt)
#pragma unroll
      for (int nt = 0; nt < 2; ++nt)
#pragma unroll
        for (int r = 0; r < 4; ++r) {
          int row = mt * 16 + lg * 4 + r;
          if (row < QPB + CC)
            u_all[row * H1 + (w * 2 + nt) * 16 + lr] = f2b(ua[mt][nt][r]);
        }
  }
  __syncthreads();

  if (t < 256) {
    float s = 0.f;
#pragma unroll
    for (int c2 = 0; c2 < CC; ++c2)
      s = fmaf(stc[1 + c2], b2f(u_all[(QPB + c2) * H1 + t]), s);
    float h = fmaxf(fmaf(stc[0], s, b1l[t]), 0.f);
    hb[(((20 * 256) + (t & ~7)) ^ 32) + (t & 7)] = f2b(h);
  }

#pragma unroll 4
  for (int i = 0; i < 12; ++i) {
    int ch = t + 512 * i;
    int r = ch >> 5, jc = ch & 31;
    int q = r / 24, c = r - q * 24;
    int j0 = jc * 8;
    int cs = (c < CC) ? c : 0;
    float al = stc[1 + CP + c];
    float dc = stc[1 + cs], sc = dc * dc;
    const v8s uv = *(const v8s*)&u_all[q * H1 + j0];
    const v8s ev = *(const v8s*)&u_all[(QPB + cs) * H1 + j0];
    __align__(16) unsigned short o[8];
#pragma unroll
    for (int e = 0; e < 8; ++e) {
      float u = b2f((unsigned short)uv[e]);
      float x = b2f((unsigned short)ev[e]);
      o[e] = f2b(fmaxf(fmaf(al, u, fmaf(sc, x, b1l[j0 + e])), 0.f));
    }
    if (r != 20)
      *(v8s*)&hb[(r * 256 + j0) ^ ((r & 7) << 3)] = *(const v8s*)o;
  }
  __syncthreads();

  int wm = w >> 2, wn = w & 3;
  v4f acc[6][2];
#pragma unroll
  for (int mt = 0; mt < 6; ++mt) {
    acc[mt][0] = (v4f){0.f, 0.f, 0.f, 0.f};
    acc[mt][1] = (v4f){0.f, 0.f, 0.f, 0.f};
  }
#pragma unroll
  for (int ks = 0; ks < 8; ++ks) {
    const v8s bb0 = *(const v8s*)&w2f[(((wn * 2 + 0) * 8) + ks) * 512 + l * 8];
    const v8s bb1 = *(const v8s*)&w2f[(((wn * 2 + 1) * 8) + ks) * 512 + l * 8];
#pragma unroll
    for (int mt = 0; mt < 6; ++mt) {
      int row = wm * 96 + mt * 16 + lr;
      const v8s a = *(const v8s*)&hb[(row * 256 + ks * 32 + lg * 8) ^ ((row & 7) << 3)];
      acc[mt][0] = __builtin_amdgcn_mfma_f32_16x16x32_bf16(a, bb0, acc[mt][0], 0, 0, 0);
      acc[mt][1] = __builtin_amdgcn_mfma_f32_16x16x32_bf16(a, bb1, acc[mt][1], 0, 0, 0);
    }
  }
  __syncthreads();

#pragma unroll
  for (int mt = 0; mt < 6; ++mt)
#pragma unroll
    for (int nt = 0; nt < 2; ++nt)
#pragma unroll
      for (int r = 0; r < 4; ++r)
        Pm[(wm * 96 + mt * 16 + lg * 4 + r) * PSTR + (wn * 2 + nt) * 16 + lr]
            = acc[mt][nt][r];
  __syncthreads();

#pragma unroll
  for (int rep = 0; rep < 2; ++rep) {
    int idx = t + 512 * rep;
    int q = idx >> 7, k = idx & 127;
    float s = 0.f;
#pragma unroll
    for (int c = 0; c < CC; ++c) s = fmaf(stc[1 + 3 * CP + c], Pm[(q * 24 + c) * PSTR + k], s);
    qe[q * H2 + k] = fmaxf(fmaf(stc[0], s, b2l[k]), 0.f);
  }
  __syncthreads();

  if (t < 256) {
    int q = t >> 5, ln = t & 31;
    float s = 0.f;
#pragma unroll
    for (int i = 0; i < 4; ++i) { float e = qe[q * H2 + ln + 32 * i]; s = fmaf(e, e, s); }
    s += __shfl_xor(s, 1); s += __shfl_xor(s, 2); s += __shfl_xor(s, 4);
    s += __shfl_xor(s, 8); s += __shfl_xor(s, 16);
    if (ln == 0) qn[q] = s;
  }
  __syncthreads();

#pragma unroll
  for (int rep = 0; rep < 2; ++rep) {
    int idx = t + 512 * rep;
    int q = idx >> 7;
    int sub = idx & 127, c = sub >> 2, lcl = sub & 3;
    if (c < CC && q0 + q < Q) {
      float num = 0.f, pn = 0.f;
      int rowb = (q * 24 + c) * PSTR;
      float bet = stc[1 + 2 * CP + c];
      float d0dc = stc[0] * stc[1 + c];
#pragma unroll
      for (int i = 0; i < 32; ++i) {
        int k = lcl + 4 * i;
        float P = Pm[rowb + k];
        float pr = fmaxf(fmaf(bet, P, fmaf(d0dc, Pm[20 * PSTR + k], b2l[k])), 0.f);
        float e = qe[q * H2 + k];
        num = fmaf(e, pr, num); pn = fmaf(pr, pr, pn);
      }
      num += __shfl_xor(num, 1); pn += __shfl_xor(pn, 1);
      num += __shfl_xor(num, 2); pn += __shfl_xor(pn, 2);
      if (lcl == 0)
        out[(size_t)(q0 + q) * CC + c] = num / fmaxf(sqrtf(qn[q]) * sqrtf(pn), 1e-8f);
    }
  }
}

// ================= legacy f32 fallback (ws too small) =================
__global__ __launch_bounds__(256) void k_convfb(
    const float* __restrict__ Sf, const int* __restrict__ labels, int S,
    float* __restrict__ SumF, float* __restrict__ stats) {
  int b = blockIdx.x, t = threadIdx.x;
  if (b < CC) {
    __shared__ int lab[128];
    if (t < S && t < 128) lab[t] = labels[t];
    __syncthreads();
    for (int d = t; d < DD; d += 256) {
      float acc = 0.f;
      for (int j = 0; j < S; ++j)
        if (lab[j] == b) acc += Sf[(size_t)j * DD + d];
      SumF[b * DD + d] = acc;
    }
  } else {
    stats_store(labels, S, stats, t);
  }
}

__global__ __launch_bounds__(256) void k_p2a(
    const float* __restrict__ SumF, const float* __restrict__ W1,
    float* __restrict__ part) {
  int c = blockIdx.x >> 2, dc = blockIdx.x & 3;
  int n = threadIdx.x;
  int d0 = dc * DCH;
  const float* __restrict__ A  = SumF + c * DD + d0;
  const float* __restrict__ Wp = W1 + (size_t)d0 * H1 + n;
  float acc = 0.f;
#pragma unroll 8
  for (int d = 0; d < DCH; ++d)
    acc = fmaf(A[d], Wp[(size_t)d * H1], acc);
  part[(c * NDC + dc) * H1 + n] = acc;
}

__global__ __launch_bounds__(256) void k_p2r(
    const float* __restrict__ part, const float* __restrict__ b1,
    const float* __restrict__ stats, float* __restrict__ B1c,
    float* __restrict__ h10) {
  int b = blockIdx.x, n = threadIdx.x;
  if (b < CC) {
    float dot = part[(b * NDC + 0) * H1 + n] + part[(b * NDC + 1) * H1 + n]
              + part[(b * NDC + 2) * H1 + n] + part[(b * NDC + 3) * H1 + n];
    float dis = stats[1 + b];
    B1c[b * H1 + n] = fmaf(dis * dis, dot, b1[n]);
  } else {
#pragma unroll
    for (int c = CC; c < CP; ++c) B1c[c * H1 + n] = 0.f;
    float s = 0.f;
#pragma unroll 4
    for (int c = 0; c < CC; ++c) {
      float dot = part[(c * NDC + 0) * H1 + n] + part[(c * NDC + 1) * H1 + n]
                + part[(c * NDC + 2) * H1 + n] + part[(c * NDC + 3) * H1 + n];
      s = fmaf(stats[1 + c], dot, s);
    }
    h10[n] = fmaxf(fmaf(stats[0], s, b1[n]), 0.f);
  }
}

__global__ __launch_bounds__(256) void k_pre2(
    const float* __restrict__ h10, const float* __restrict__ W2,
    const float* __restrict__ b2, const float* __restrict__ stats,
    float* __restrict__ pre) {
  __shared__ float red[256];
  int t = threadIdx.x, k = t & 127, jh = t >> 7;
  float g = 0.f;
#pragma unroll 8
  for (int j = jh * 128; j < jh * 128 + 128; ++j)
    g = fmaf(h10[j], W2[j * H2 + k], g);
  red[t] = g;
  __syncthreads();
  if (t < 128) {
    g = red[t] + red[t + 128];
    float d0 = stats[0], bb = b2[k];
#pragma unroll
    for (int c = 0; c < CC; ++c)
      pre[c * H2 + k] = fmaf(d0 * stats[1 + c], g, bb);
  }
}

__global__ __launch_bounds__(256) void k_fb(
    const float* __restrict__ qf, const float* __restrict__ W1,
    const float* __restrict__ W2, const float* __restrict__ b2,
    const float* __restrict__ B1c, const float* __restrict__ pre_ck,
    const float* __restrict__ stats, float* __restrict__ out, int Q) {
  __shared__ __align__(16) float h1[CP][H1];
  __shared__ __align__(16) float proto[CC][H2 + 4];
  __shared__ __align__(16) float psum[8][H2];
  __shared__ float qel[H2];
  __shared__ float stc[NSTAT];
  int tid = threadIdx.x, q = blockIdx.x;
  if (tid < NSTAT) stc[tid] = stats[tid];
  float uvacc = 0.f;
  for (int d = 0; d < DD; ++d) uvacc += qf[(size_t)q * DD + d] * W1[d * H1 + tid];
  __syncthreads();
#pragma unroll
  for (int r = 0; r < CP; ++r)
    h1[r][tid] = fmaxf(stc[1 + CP + r] * uvacc + B1c[r * H1 + tid], 0.f);
  __syncthreads();
  int sg = tid >> 5, kq = tid & 31, k4 = kq * 4, cb = sg * 3;
  float a[3][4];
#pragma unroll
  for (int i = 0; i < 3; ++i)
#pragma unroll
    for (int kk = 0; kk < 4; ++kk) a[i][kk] = 0.f;
  const float4* W2v = (const float4*)W2;
#pragma unroll 2
  for (int j0 = 0; j0 < H1; j0 += 4) {
    float wv[4][4]; float4 hh[3];
#pragma unroll
    for (int jj = 0; jj < 4; ++jj) {
      float4 tv = W2v[(j0 + jj) * 32 + kq];
      wv[jj][0] = tv.x; wv[jj][1] = tv.y; wv[jj][2] = tv.z; wv[jj][3] = tv.w;
    }
#pragma unroll
    for (int i = 0; i < 3; ++i) hh[i] = *(const float4*)&h1[cb + i][j0];
#pragma unroll
    for (int i = 0; i < 3; ++i)
#pragma unroll
      for (int jj = 0; jj < 4; ++jj) {
        float h = ((const float*)&hh[i])[jj];
#pragma unroll
        for (int kk = 0; kk < 4; ++kk) a[i][kk] = fmaf(h, wv[jj][kk], a[i][kk]);
      }
  }
  {
    __align__(16) float part[4] = {0.f, 0.f, 0.f, 0.f};
#pragma unroll
    for (int i = 0; i < 3; ++i) {
      int c = cb + i;
      float gam = stc[1 + 3 * CP + c];
#pragma unroll
      for (int kk = 0; kk < 4; ++kk) part[kk] += gam * a[i][kk];
      if (c < CC) {
        float bet = stc[1 + 2 * CP + c];
        float4 pv = *(const float4*)&pre_ck[c * H2 + k4];
        float4 pr;
        pr.x = fmaxf(pv.x + bet * a[i][0], 0.f);
        pr.y = fmaxf(pv.y + bet * a[i][1], 0.f);
        pr.z = fmaxf(pv.z + bet * a[i][2], 0.f);
        pr.w = fmaxf(pv.w + bet * a[i][3], 0.f);
        *(float4*)&proto[c][k4] = pr;
      }
    }
    *(float4*)&psum[sg][k4] = *(const float4*)part;
  }
  __syncthreads();
  if (tid < H2) {
    float s = 0.f;
#pragma unroll
    for (int g = 0; g < 8; ++g) s += psum[g][tid];
    qel[tid] = fmaxf(stc[0] * s + b2[tid], 0.f);
  }
  __syncthreads();
  if (tid < 160) {
    int c = tid >> 3, ln = tid & 7;
    float num = 0.f, pn = 0.f, qnn = 0.f;
#pragma unroll
    for (int i = 0; i < 16; ++i) {
      int k = ln + 8 * i;
      float e = qel[k], p = proto[c][k];
      num = fmaf(e, p, num); pn = fmaf(p, p, pn); qnn = fmaf(e, e, qnn);
    }
    num += __shfl_xor(num, 1); pn += __shfl_xor(pn, 1); qnn += __shfl_xor(qnn, 1);
    num += __shfl_xor(num, 2); pn += __shfl_xor(pn, 2); qnn += __shfl_xor(qnn, 2);
    num += __shfl_xor(num, 4); pn += __shfl_xor(pn, 4); qnn += __shfl_xor(qnn, 4);
    if (ln == 0)
      out[(size_t)q * CC + c] = num / fmaxf(sqrtf(qnn) * sqrtf(pn), 1e-8f);
  }
}

extern "C" void kernel_launch(void* const* d_in, const int* in_sizes, int n_in,
                              void* d_out, int out_size, void* d_ws, size_t ws_size,
                              hipStream_t stream) {
  const float* Sf     = (const float*)d_in[0];
  const int*   labels = (const int*)d_in[1];
  const float* qf     = (const float*)d_in[2];
  const float* W1     = (const float*)d_in[3];
  const float* b1     = (const float*)d_in[4];
  const float* W2     = (const float*)d_in[5];
  const float* b2     = (const float*)d_in[6];
  int S = in_sizes[1];
  int Q = in_sizes[2] / DD;

  float* ws  = (float*)d_ws;
  float* out = (float*)d_out;

  if (ws_size >= (size_t)REQ_FAST * sizeof(float)) {
    float*          stats = ws + OFF_ST2;
    unsigned short* qbc   = (unsigned short*)(ws + OFF_QBC);
    unsigned short* w1f   = (unsigned short*)(ws + OFF_W1F);
    unsigned short* w2f   = (unsigned short*)(ws + OFF_W2F);
    unsigned int*   mrk   = (unsigned int*)(ws + OFF_MRK);
    int nb = (Q + QPB - 1) / QPB;
    if (nb >= NPROD && nb <= 256) {
      // single fused launch: 1 block/CU (101KB LDS forbids stacking) -> all blocks
      // co-resident -> marker spin-wait is starvation-free by construction.
      k_fused<<<dim3(nb), dim3(512), 0, stream>>>(
          Sf, labels, S, qf, W1, W2, b1, b2, qbc, w1f, w2f, stats, mrk, out, Q);
    } else {
      k_conv2<<<dim3(CSB + 1 + 64 + 16), dim3(256), 0, stream>>>(
          Sf, labels, S, W1, W2, qbc, w1f, w2f, stats);
      k_main<<<dim3(nb), dim3(512), 0, stream>>>(
          qf, b1, b2, qbc, w1f, w2f, stats, out, Q);
    }
  } else {
    float* SumF  = ws + OFF_SUMF;
    float* B1c   = ws + OFF_B1C;
    float* h10   = ws + OFF_H10;
    float* pre   = ws + OFF_PRE;
    float* stats = ws + OFF_ST;
    float* part  = ws + OFF_U;
    k_convfb<<<dim3(CC + 1), dim3(256), 0, stream>>>(Sf, labels, S, SumF, stats);
    k_p2a<<<dim3(CC * NDC), dim3(256), 0, stream>>>(SumF, W1, part);
    k_p2r<<<dim3(CC + 1), dim3(256), 0, stream>>>(part, b1, stats, B1c, h10);
    k_pre2<<<dim3(1), dim3(256), 0, stream>>>(h10, W2, b2, stats, pre);
    k_fb<<<dim3(Q), dim3(256), 0, stream>>>(qf, W1, W2, b2, B1c, pre, stats, out, Q);
  }
}

// Round 16
// 29.255 us; speedup vs baseline: 1.2363x; 1.2363x over previous
//
#include <hip/hip_runtime.h>
#include <hip/hip_bf16.h>

#define DD 512   // feature dim
#define H1 256   // hidden 1
#define H2 128   // hidden 2
#define CC 20    // real classes
#define CP 24    // padded classes
#define QPB 8    // queries per block in k_main (512 threads)
#define HROWS (QPB*CP)   // 192 h1 rows per block
#define PSTR 132         // Pmat row stride (floats)
#define NDC 4            // fallback split-K
#define DCH (DD/NDC)
#define CSB 40           // class-sum blocks (2 per class)

typedef short v8s __attribute__((ext_vector_type(8)));
typedef float v4f __attribute__((ext_vector_type(4)));

// ---- fast-path ws float offsets ----
#define NSTAT    97
#define OFF_ST2  0
#define OFF_QBC  128                   // 20x512 bf16 = 5120 float slots
#define OFF_W1F  5248                  // 131072 bf16 = 65536 float slots
#define OFF_W2F  70784                 // 32768 bf16 = 16384 float slots
#define REQ_FAST 87168
// ---- fallback ws float offsets (legacy) ----
#define OFF_SUMF 0
#define OFF_B1C  10240
#define OFF_H10  16384
#define OFF_PRE  16640
#define OFF_ST   19200
#define OFF_U    19328

static __device__ __forceinline__ unsigned short f2b(float f) {
  return __bfloat16_as_ushort(__float2bfloat16(f));
}
static __device__ __forceinline__ float b2f(unsigned short s) {
  return __bfloat162float(__ushort_as_bfloat16(s));
}

static __device__ __forceinline__ void stats_store(
    const int* __restrict__ labels, int S, float* __restrict__ stats, int t) {
  if (t < CP) {
    int cnt = 0;
    for (int j = 0; j < S; ++j) if (labels[j] == t) cnt++;
    float deg  = 1.f + (float)cnt;
    float dis  = rsqrtf(deg + 1e-6f);
    float dis0 = rsqrtf((float)S + 1e-6f);
    stats[1 + t]          = dis;
    stats[1 + CP + t]     = dis0 * dis;               // alpha
    stats[1 + 2*CP + t]   = dis * dis * (float)cnt;   // beta (0 pad)
    stats[1 + 3*CP + t]   = dis * (float)cnt;         // gamma (0 pad)
    if (t == 0) stats[0] = dis0;
  }
}

static __device__ __forceinline__ void w1frag_store(
    const float* __restrict__ W1, unsigned short* __restrict__ w1f, int frag, int l) {
  int lr = l & 15, lg = l >> 4;
  int nt = frag >> 4, ks = frag & 15;
  __align__(16) unsigned short o[8];
#pragma unroll
  for (int e = 0; e < 8; ++e)
    o[e] = f2b(W1[(ks * 32 + lg * 8 + e) * H1 + nt * 16 + lr]);
  *(v8s*)&w1f[frag * 512 + l * 8] = *(const v8s*)o;
}

static __device__ __forceinline__ void w2frag_store(
    const float* __restrict__ W2, unsigned short* __restrict__ w2f, int frag, int l) {
  int lr = l & 15, lg = l >> 4;
  int nt = frag >> 3, ks = frag & 7;
  __align__(16) unsigned short o[8];
#pragma unroll
  for (int e = 0; e < 8; ++e)
    o[e] = f2b(W2[(ks * 32 + lg * 8 + e) * H2 + nt * 16 + lr]);
  *(v8s*)&w2f[frag * 512 + l * 8] = *(const v8s*)o;
}

// ============ k_conv2: class sums (bf16, 2 blocks/class), stats, W1/W2 frag pre-swizzle ====
__global__ __launch_bounds__(256) void k_conv2(
    const float* __restrict__ Sf, const int* __restrict__ labels, int S,
    const float* __restrict__ W1, const float* __restrict__ W2,
    unsigned short* __restrict__ qbc, unsigned short* __restrict__ w1f,
    unsigned short* __restrict__ w2f, float* __restrict__ stats) {
  int b = blockIdx.x, t = threadIdx.x;
  if (b < CSB) {
    __shared__ int lab[128];
    if (t < S && t < 128) lab[t] = labels[t];
    __syncthreads();
    int c = b >> 1;
    int d = (b & 1) * 256 + t;
    float acc = 0.f;
    for (int j = 0; j < S; ++j)
      if (lab[j] == c) acc += Sf[(size_t)j * DD + d];   // wave-uniform branch
    qbc[c * DD + d] = f2b(acc);
  } else if (b == CSB) {
    stats_store(labels, S, stats, t);
  } else if (b < CSB + 1 + 64) {
    w1frag_store(W1, w1f, (b - CSB - 1) * 4 + (t >> 6), t & 63);
  } else {
    w2frag_store(W2, w2f, (b - CSB - 1 - 64) * 4 + (t >> 6), t & 63);
  }
}

// ============ k_main: 8 queries/block, 512 threads, per-block U-GEMM + fused pipeline ====
__global__ __launch_bounds__(512, 1) void k_main(
    const float* __restrict__ qf,
    const float* __restrict__ b1, const float* __restrict__ b2,
    const unsigned short* __restrict__ qbc, const unsigned short* __restrict__ w1f,
    const unsigned short* __restrict__ w2f, const float* __restrict__ stats,
    float* __restrict__ out, int Q) {
  __shared__ float smem[HROWS * PSTR];           // 101.4KB: A-tile, then hb/Pm (aliased)
  __shared__ unsigned short u_all[28 * H1];      // 14KB bf16 U rows (8q + 20c)
  __shared__ float stc[NSTAT];
  __shared__ __align__(16) float b1l[H1];
  __shared__ float b2l[H2];
  __shared__ float qe[QPB * H2];
  __shared__ float qn[QPB];
  unsigned short* ab = (unsigned short*)smem;    // A-tile bf16 [32][512], XOR-swizzled
  unsigned short* hb = (unsigned short*)smem;    // h1 bf16 [192][256], XOR-swizzled
  float* Pm = smem;

  int t = threadIdx.x, q0 = blockIdx.x * QPB;
  if (t < NSTAT) stc[t] = stats[t];
  if (t < H1) b1l[t] = b1[t];
  if (t >= 128 && t < 256) b2l[t - 128] = b2[t - 128];

  // ---- stage A-tile: rows 0-7 = queries, 8-27 = class rows, 28-31 pad ----
#pragma unroll
  for (int i = 0; i < 4; ++i) {
    int ch = t + 512 * i;
    int row = ch >> 6, jc = ch & 63;
    __align__(16) unsigned short o[8];
    if (row < QPB) {
      if (q0 + row < Q) {
        const float4 a = *(const float4*)&qf[(size_t)(q0 + row) * DD + jc * 8];
        const float4 c = *(const float4*)&qf[(size_t)(q0 + row) * DD + jc * 8 + 4];
        o[0]=f2b(a.x); o[1]=f2b(a.y); o[2]=f2b(a.z); o[3]=f2b(a.w);
        o[4]=f2b(c.x); o[5]=f2b(c.y); o[6]=f2b(c.z); o[7]=f2b(c.w);
      } else {
#pragma unroll
        for (int e = 0; e < 8; ++e) o[e] = 0;
      }
      *(v8s*)&ab[(row * DD + jc * 8) ^ ((row & 7) << 3)] = *(const v8s*)o;
    } else if (row < QPB + CC) {
      v8s v = *(const v8s*)&qbc[(row - QPB) * DD + jc * 8];
      *(v8s*)&ab[(row * DD + jc * 8) ^ ((row & 7) << 3)] = v;
    } else {
      v8s z = (v8s){0,0,0,0,0,0,0,0};
      *(v8s*)&ab[(row * DD + jc * 8) ^ ((row & 7) << 3)] = z;
    }
  }
  __syncthreads();

  // ---- U-GEMM: [32 x 512] @ W1 -> u_all[28][256]; wave w owns N-tiles {2w, 2w+1} ----
  int w = t >> 6, l = t & 63, lr = l & 15, lg = l >> 4;
  {
    v4f ua[2][2];
#pragma unroll
    for (int mt = 0; mt < 2; ++mt)
#pragma unroll
      for (int nt = 0; nt < 2; ++nt) ua[mt][nt] = (v4f){0.f, 0.f, 0.f, 0.f};
#pragma unroll 2
    for (int ks = 0; ks < 16; ++ks) {
      const v8s a0 = *(const v8s*)&ab[((0  + lr) * DD + ks * 32 + lg * 8) ^ ((lr & 7) << 3)];
      const v8s a1 = *(const v8s*)&ab[((16 + lr) * DD + ks * 32 + lg * 8) ^ ((lr & 7) << 3)];
#pragma unroll
      for (int nt = 0; nt < 2; ++nt) {
        const v8s bb = *(const v8s*)&w1f[((w * 2 + nt) * 16 + ks) * 512 + l * 8];
        ua[0][nt] = __builtin_amdgcn_mfma_f32_16x16x32_bf16(a0, bb, ua[0][nt], 0, 0, 0);
        ua[1][nt] = __builtin_amdgcn_mfma_f32_16x16x32_bf16(a1, bb, ua[1][nt], 0, 0, 0);
      }
    }
#pragma unroll
    for (int mt = 0; mt < 2; ++mt)
#pragma unroll
      for (int nt = 0; nt < 2; ++nt)
#pragma unroll
        for (int r = 0; r < 4; ++r) {
          int row = mt * 16 + lg * 4 + r;
          if (row < QPB + CC)
            u_all[row * H1 + (w * 2 + nt) * 16 + lr] = f2b(ua[mt][nt][r]);
        }
  }
  __syncthreads();   // A-tile dead; u_all ready; smem free for hb

  // ---- h10 row (hb row 20, q=0 pad slot, gamma=0): 256 threads in parallel ----
  if (t < 256) {
    float s = 0.f;
#pragma unroll
    for (int c2 = 0; c2 < CC; ++c2)
      s = fmaf(stc[1 + c2], b2f(u_all[(QPB + c2) * H1 + t]), s);
    float h = fmaxf(fmaf(stc[0], s, b1l[t]), 0.f);
    hb[(((20 * 256) + (t & ~7)) ^ 32) + (t & 7)] = f2b(h);
  }

  // ---- h1 build (bf16, XOR-swizzled); r==20 handled above ----
#pragma unroll 4
  for (int i = 0; i < 12; ++i) {
    int ch = t + 512 * i;
    int r = ch >> 5, jc = ch & 31;
    int q = r / 24, c = r - q * 24;
    int j0 = jc * 8;
    int cs = (c < CC) ? c : 0;                   // clamp pad rows (finite, unused)
    float al = stc[1 + CP + c];
    float dc = stc[1 + cs], sc = dc * dc;
    const v8s uv = *(const v8s*)&u_all[q * H1 + j0];
    const v8s ev = *(const v8s*)&u_all[(QPB + cs) * H1 + j0];
    __align__(16) unsigned short o[8];
#pragma unroll
    for (int e = 0; e < 8; ++e) {
      float u = b2f((unsigned short)uv[e]);
      float x = b2f((unsigned short)ev[e]);
      o[e] = f2b(fmaxf(fmaf(al, u, fmaf(sc, x, b1l[j0 + e])), 0.f));
    }
    if (r != 20)
      *(v8s*)&hb[(r * 256 + j0) ^ ((r & 7) << 3)] = *(const v8s*)o;
  }
  __syncthreads();

  // ---- P-GEMM: 2D wave split: (wm,wn) = (w>>2, w&3); 6 M-tiles x 2 N-tiles x 8 ks ----
  int wm = w >> 2, wn = w & 3;
  v4f acc[6][2];
#pragma unroll
  for (int mt = 0; mt < 6; ++mt) {
    acc[mt][0] = (v4f){0.f, 0.f, 0.f, 0.f};
    acc[mt][1] = (v4f){0.f, 0.f, 0.f, 0.f};
  }
#pragma unroll
  for (int ks = 0; ks < 8; ++ks) {
    const v8s bb0 = *(const v8s*)&w2f[(((wn * 2 + 0) * 8) + ks) * 512 + l * 8];
    const v8s bb1 = *(const v8s*)&w2f[(((wn * 2 + 1) * 8) + ks) * 512 + l * 8];
#pragma unroll
    for (int mt = 0; mt < 6; ++mt) {
      int row = wm * 96 + mt * 16 + lr;
      const v8s a = *(const v8s*)&hb[(row * 256 + ks * 32 + lg * 8) ^ ((row & 7) << 3)];
      acc[mt][0] = __builtin_amdgcn_mfma_f32_16x16x32_bf16(a, bb0, acc[mt][0], 0, 0, 0);
      acc[mt][1] = __builtin_amdgcn_mfma_f32_16x16x32_bf16(a, bb1, acc[mt][1], 0, 0, 0);
    }
  }
  __syncthreads();   // hb reads done -> alias as Pmat

#pragma unroll
  for (int mt = 0; mt < 6; ++mt)
#pragma unroll
    for (int nt = 0; nt < 2; ++nt)
#pragma unroll
      for (int r = 0; r < 4; ++r)
        Pm[(wm * 96 + mt * 16 + lg * 4 + r) * PSTR + (wn * 2 + nt) * 16 + lr]
            = acc[mt][nt][r];
  __syncthreads();
  // Pm[20][k] == g2[k] = h10 @ W2[:,k]

#pragma unroll
  for (int rep = 0; rep < 2; ++rep) {
    int idx = t + 512 * rep;
    int q = idx >> 7, k = idx & 127;
    float s = 0.f;
#pragma unroll
    for (int c = 0; c < CC; ++c) s = fmaf(stc[1 + 3 * CP + c], Pm[(q * 24 + c) * PSTR + k], s);
    qe[q * H2 + k] = fmaxf(fmaf(stc[0], s, b2l[k]), 0.f);
  }
  __syncthreads();

  if (t < 256) {
    int q = t >> 5, ln = t & 31;
    float s = 0.f;
#pragma unroll
    for (int i = 0; i < 4; ++i) { float e = qe[q * H2 + ln + 32 * i]; s = fmaf(e, e, s); }
    s += __shfl_xor(s, 1); s += __shfl_xor(s, 2); s += __shfl_xor(s, 4);
    s += __shfl_xor(s, 8); s += __shfl_xor(s, 16);
    if (ln == 0) qn[q] = s;
  }
  __syncthreads();

#pragma unroll
  for (int rep = 0; rep < 2; ++rep) {
    int idx = t + 512 * rep;
    int q = idx >> 7;
    int sub = idx & 127, c = sub >> 2, lcl = sub & 3;
    if (c < CC && q0 + q < Q) {
      float num = 0.f, pn = 0.f;
      int rowb = (q * 24 + c) * PSTR;
      float bet = stc[1 + 2 * CP + c];
      float d0dc = stc[0] * stc[1 + c];
#pragma unroll
      for (int i = 0; i < 32; ++i) {
        int k = lcl + 4 * i;
        float P = Pm[rowb + k];
        float pr = fmaxf(fmaf(bet, P, fmaf(d0dc, Pm[20 * PSTR + k], b2l[k])), 0.f);
        float e = qe[q * H2 + k];
        num = fmaf(e, pr, num); pn = fmaf(pr, pr, pn);
      }
      num += __shfl_xor(num, 1); pn += __shfl_xor(pn, 1);
      num += __shfl_xor(num, 2); pn += __shfl_xor(pn, 2);
      if (lcl == 0)
        out[(size_t)(q0 + q) * CC + c] = num / fmaxf(sqrtf(qn[q]) * sqrtf(pn), 1e-8f);
    }
  }
}

// ================= fallback path (ws too small) — r6-proven f32 chain =================
__global__ __launch_bounds__(256) void k_convfb(
    const float* __restrict__ Sf, const int* __restrict__ labels, int S,
    float* __restrict__ SumF, float* __restrict__ stats) {
  int b = blockIdx.x, t = threadIdx.x;
  if (b < CC) {
    __shared__ int lab[128];
    if (t < S && t < 128) lab[t] = labels[t];
    __syncthreads();
    for (int d = t; d < DD; d += 256) {
      float acc = 0.f;
      for (int j = 0; j < S; ++j)
        if (lab[j] == b) acc += Sf[(size_t)j * DD + d];
      SumF[b * DD + d] = acc;
    }
  } else {
    stats_store(labels, S, stats, t);
  }
}

__global__ __launch_bounds__(256) void k_p2a(
    const float* __restrict__ SumF, const float* __restrict__ W1,
    float* __restrict__ part) {
  int c = blockIdx.x >> 2, dc = blockIdx.x & 3;
  int n = threadIdx.x;
  int d0 = dc * DCH;
  const float* __restrict__ A  = SumF + c * DD + d0;
  const float* __restrict__ Wp = W1 + (size_t)d0 * H1 + n;
  float acc = 0.f;
#pragma unroll 8
  for (int d = 0; d < DCH; ++d)
    acc = fmaf(A[d], Wp[(size_t)d * H1], acc);
  part[(c * NDC + dc) * H1 + n] = acc;
}

__global__ __launch_bounds__(256) void k_p2r(
    const float* __restrict__ part, const float* __restrict__ b1,
    const float* __restrict__ stats, float* __restrict__ B1c,
    float* __restrict__ h10) {
  int b = blockIdx.x, n = threadIdx.x;
  if (b < CC) {
    float dot = part[(b * NDC + 0) * H1 + n] + part[(b * NDC + 1) * H1 + n]
              + part[(b * NDC + 2) * H1 + n] + part[(b * NDC + 3) * H1 + n];
    float dis = stats[1 + b];
    B1c[b * H1 + n] = fmaf(dis * dis, dot, b1[n]);
  } else {
#pragma unroll
    for (int c = CC; c < CP; ++c) B1c[c * H1 + n] = 0.f;
    float s = 0.f;
#pragma unroll 4
    for (int c = 0; c < CC; ++c) {
      float dot = part[(c * NDC + 0) * H1 + n] + part[(c * NDC + 1) * H1 + n]
                + part[(c * NDC + 2) * H1 + n] + part[(c * NDC + 3) * H1 + n];
      s = fmaf(stats[1 + c], dot, s);
    }
    h10[n] = fmaxf(fmaf(stats[0], s, b1[n]), 0.f);
  }
}

__global__ __launch_bounds__(256) void k_pre2(
    const float* __restrict__ h10, const float* __restrict__ W2,
    const float* __restrict__ b2, const float* __restrict__ stats,
    float* __restrict__ pre) {
  __shared__ float red[256];
  int t = threadIdx.x, k = t & 127, jh = t >> 7;
  float g = 0.f;
#pragma unroll 8
  for (int j = jh * 128; j < jh * 128 + 128; ++j)
    g = fmaf(h10[j], W2[j * H2 + k], g);
  red[t] = g;
  __syncthreads();
  if (t < 128) {
    g = red[t] + red[t + 128];
    float d0 = stats[0], bb = b2[k];
#pragma unroll
    for (int c = 0; c < CC; ++c)
      pre[c * H2 + k] = fmaf(d0 * stats[1 + c], g, bb);
  }
}

__global__ __launch_bounds__(256) void k_fb(
    const float* __restrict__ qf, const float* __restrict__ W1,
    const float* __restrict__ W2, const float* __restrict__ b2,
    const float* __restrict__ B1c, const float* __restrict__ pre_ck,
    const float* __restrict__ stats, float* __restrict__ out, int Q) {
  __shared__ __align__(16) float h1[CP][H1];
  __shared__ __align__(16) float proto[CC][H2 + 4];
  __shared__ __align__(16) float psum[8][H2];
  __shared__ float qel[H2];
  __shared__ float stc[NSTAT];
  int tid = threadIdx.x, q = blockIdx.x;
  if (tid < NSTAT) stc[tid] = stats[tid];
  float uvacc = 0.f;
  for (int d = 0; d < DD; ++d) uvacc += qf[(size_t)q * DD + d] * W1[d * H1 + tid];
  __syncthreads();
#pragma unroll
  for (int r = 0; r < CP; ++r)
    h1[r][tid] = fmaxf(stc[1 + CP + r] * uvacc + B1c[r * H1 + tid], 0.f);
  __syncthreads();
  int sg = tid >> 5, kq = tid & 31, k4 = kq * 4, cb = sg * 3;
  float a[3][4];
#pragma unroll
  for (int i = 0; i < 3; ++i)
#pragma unroll
    for (int kk = 0; kk < 4; ++kk) a[i][kk] = 0.f;
  const float4* W2v = (const float4*)W2;
#pragma unroll 2
  for (int j0 = 0; j0 < H1; j0 += 4) {
    float wv[4][4]; float4 hh[3];
#pragma unroll
    for (int jj = 0; jj < 4; ++jj) {
      float4 tv = W2v[(j0 + jj) * 32 + kq];
      wv[jj][0] = tv.x; wv[jj][1] = tv.y; wv[jj][2] = tv.z; wv[jj][3] = tv.w;
    }
#pragma unroll
    for (int i = 0; i < 3; ++i) hh[i] = *(const float4*)&h1[cb + i][j0];
#pragma unroll
    for (int i = 0; i < 3; ++i)
#pragma unroll
      for (int jj = 0; jj < 4; ++jj) {
        float h = ((const float*)&hh[i])[jj];
#pragma unroll
        for (int kk = 0; kk < 4; ++kk) a[i][kk] = fmaf(h, wv[jj][kk], a[i][kk]);
      }
  }
  {
    __align__(16) float part[4] = {0.f, 0.f, 0.f, 0.f};
#pragma unroll
    for (int i = 0; i < 3; ++i) {
      int c = cb + i;
      float gam = stc[1 + 3 * CP + c];
#pragma unroll
      for (int kk = 0; kk < 4; ++kk) part[kk] += gam * a[i][kk];
      if (c < CC) {
        float bet = stc[1 + 2 * CP + c];
        float4 pv = *(const float4*)&pre_ck[c * H2 + k4];
        float4 pr;
        pr.x = fmaxf(pv.x + bet * a[i][0], 0.f);
        pr.y = fmaxf(pv.y + bet * a[i][1], 0.f);
        pr.z = fmaxf(pv.z + bet * a[i][2], 0.f);
        pr.w = fmaxf(pv.w + bet * a[i][3], 0.f);
        *(float4*)&proto[c][k4] = pr;
      }
    }
    *(float4*)&psum[sg][k4] = *(const float4*)part;
  }
  __syncthreads();
  if (tid < H2) {
    float s = 0.f;
#pragma unroll
    for (int g = 0; g < 8; ++g) s += psum[g][tid];
    qel[tid] = fmaxf(stc[0] * s + b2[tid], 0.f);
  }
  __syncthreads();
  if (tid < 160) {
    int c = tid >> 3, ln = tid & 7;
    float num = 0.f, pn = 0.f, qnn = 0.f;
#pragma unroll
    for (int i = 0; i < 16; ++i) {
      int k = ln + 8 * i;
      float e = qel[k], p = proto[c][k];
      num = fmaf(e, p, num); pn = fmaf(p, p, pn); qnn = fmaf(e, e, qnn);
    }
    num += __shfl_xor(num, 1); pn += __shfl_xor(pn, 1); qnn += __shfl_xor(qnn, 1);
    num += __shfl_xor(num, 2); pn += __shfl_xor(pn, 2); qnn += __shfl_xor(qnn, 2);
    num += __shfl_xor(num, 4); pn += __shfl_xor(pn, 4); qnn += __shfl_xor(qnn, 4);
    if (ln == 0)
      out[(size_t)q * CC + c] = num / fmaxf(sqrtf(qnn) * sqrtf(pn), 1e-8f);
  }
}

extern "C" void kernel_launch(void* const* d_in, const int* in_sizes, int n_in,
                              void* d_out, int out_size, void* d_ws, size_t ws_size,
                              hipStream_t stream) {
  const float* Sf     = (const float*)d_in[0];
  const int*   labels = (const int*)d_in[1];
  const float* qf     = (const float*)d_in[2];
  const float* W1     = (const float*)d_in[3];
  const float* b1     = (const float*)d_in[4];
  const float* W2     = (const float*)d_in[5];
  const float* b2     = (const float*)d_in[6];
  int S = in_sizes[1];
  int Q = in_sizes[2] / DD;

  float* ws  = (float*)d_ws;
  float* out = (float*)d_out;

  if (ws_size >= (size_t)REQ_FAST * sizeof(float)) {
    float*          stats = ws + OFF_ST2;
    unsigned short* qbc   = (unsigned short*)(ws + OFF_QBC);
    unsigned short* w1f   = (unsigned short*)(ws + OFF_W1F);
    unsigned short* w2f   = (unsigned short*)(ws + OFF_W2F);
    k_conv2<<<dim3(CSB + 1 + 64 + 16), dim3(256), 0, stream>>>(
        Sf, labels, S, W1, W2, qbc, w1f, w2f, stats);
    k_main<<<dim3((Q + QPB - 1) / QPB), dim3(512), 0, stream>>>(
        qf, b1, b2, qbc, w1f, w2f, stats, out, Q);
  } else {
    float* SumF  = ws + OFF_SUMF;
    float* B1c   = ws + OFF_B1C;
    float* h10   = ws + OFF_H10;
    float* pre   = ws + OFF_PRE;
    float* stats = ws + OFF_ST;
    float* part  = ws + OFF_U;
    k_convfb<<<dim3(CC + 1), dim3(256), 0, stream>>>(Sf, labels, S, SumF, stats);
    k_p2a<<<dim3(CC * NDC), dim3(256), 0, stream>>>(SumF, W1, part);
    k_p2r<<<dim3(CC + 1), dim3(256), 0, stream>>>(part, b1, stats, B1c, h10);
    k_pre2<<<dim3(1), dim3(256), 0, stream>>>(h10, W2, b2, stats, pre);
    k_fb<<<dim3(Q), dim3(256), 0, stream>>>(qf, W1, W2, b2, B1c, pre, stats, out, Q);
  }
}